// Round 5
// baseline (186.359 us; speedup 1.0000x reference)
//
#include <hip/hip_runtime.h>

typedef __attribute__((ext_vector_type(8))) short bf16x8;
typedef __attribute__((ext_vector_type(4))) float f32x4;
typedef __attribute__((ext_vector_type(4))) short short4v;
typedef __attribute__((ext_vector_type(4))) unsigned int u32x4;

#define DEVFN static __device__ __forceinline__

DEVFN short f2bf(float f) {
  unsigned int u = __builtin_bit_cast(unsigned int, f);
  unsigned int r = (u + 0x7FFFu + ((u >> 16) & 1u)) >> 16;   // RNE
  return (short)r;
}

DEVFN unsigned int pack2bf(float a, float b) {
  unsigned int lo = (unsigned int)(unsigned short)f2bf(a);
  unsigned int hi = (unsigned int)(unsigned short)f2bf(b);
  return lo | (hi << 16);
}

DEVFN f32x4 mfma_bf16(bf16x8 a, bf16x8 b, f32x4 c) {
  return __builtin_amdgcn_mfma_f32_16x16x32_bf16(a, b, c, 0, 0, 0);
}

DEVFN f32x4 zero4() { f32x4 z = {0.f, 0.f, 0.f, 0.f}; return z; }
DEVFN bf16x8 zero8() { bf16x8 z = {0,0,0,0,0,0,0,0}; return z; }

DEVFN void gload_lds16(const void* g, void* l) {
  __builtin_amdgcn_global_load_lds(
      (const __attribute__((address_space(1))) unsigned int*)g,
      (__attribute__((address_space(3))) unsigned int*)l, 16, 0, 0);
}

DEVFN bf16x8 lds8(const short* p) {
  short4v lo = *reinterpret_cast<const short4v*>(p);
  short4v hi = *reinterpret_cast<const short4v*>(p + 4);
  bf16x8 r;
  r[0] = lo[0]; r[1] = lo[1]; r[2] = lo[2]; r[3] = lo[3];
  r[4] = hi[0]; r[5] = hi[1]; r[6] = hi[2]; r[7] = hi[3];
  return r;
}

// ---------------------------------------------------------------------------
// Weight pack: fold BN scale, cvt bf16, fragment-major layout
// pk[((c*(O/16)+j)*64+lane)*8+e] = w[j*16+(lane&15)][c*32+(lane>>4)*8+e]*s
// ---------------------------------------------------------------------------
__global__ void pack_w_k(const float* __restrict__ w, const float* __restrict__ g,
                         const float* __restrict__ b, const float* __restrict__ m,
                         const float* __restrict__ v, short* __restrict__ pk,
                         float* __restrict__ bias, int O) {
  const int t = blockIdx.x * 256 + threadIdx.x;
  const int nt = O >> 4;
  const int total = nt * 8 * 64;
  if (t < total) {
    int lane = t & 63;
    int j = (t >> 6) % nt;
    int c = (t >> 6) / nt;
    int row = j * 16 + (lane & 15);
    int col = c * 32 + (lane >> 4) * 8;
    float s = g[row] * rsqrtf(v[row] + 1e-5f);
    const float* wp = w + (size_t)row * 256 + col;
    short* o = pk + (size_t)t * 8;
#pragma unroll
    for (int e = 0; e < 8; ++e) o[e] = f2bf(wp[e] * s);
  }
  if (t < O) {
    float s = g[t] * rsqrtf(v[t] + 1e-5f);
    bias[t] = b[t] - m[t] * s;
  }
}

// ---------------------------------------------------------------------------
// Kernel 1 (NEW): stage-once barrier-free streaming GEMM.
// Block = 512 thr (8 waves), N-slice = 128 cols (64 KB weights in LDS),
// 2 M-tiles of 128 rows per block, x register-prefetched one tile ahead.
// grid = 3 slices * 392 = 1176.
// ---------------------------------------------------------------------------
struct KvTileCtx {
  int w, lane, l15, g, j0;
  const float* __restrict__ bias;
  short* __restrict__ k_out;
  short* __restrict__ vT_out;
};

__global__ __launch_bounds__(512) void kv_gemm4(
    const float* __restrict__ x, const short* __restrict__ pk,
    const float* __restrict__ bias, short* __restrict__ k_out,
    short* __restrict__ vT_out) {
  __shared__ short bs[64 * 512];   // 64 KB: seg s=(c*8+jl): [64 lanes][8 bf16]
  const int tid = threadIdx.x, w = tid >> 6, lane = tid & 63;
  const int l15 = lane & 15, g = lane >> 4;
  const int slice = blockIdx.x % 3;
  const int tidx  = blockIdx.x / 3;      // 0..391
  const int j0 = slice * 8;

  // stage this slice's weights once: 64 segs of 1 KB
  for (int s = w; s < 64; s += 8) {
    int c = s >> 3, jl = s & 7;
    gload_lds16(pk + ((size_t)(c * 24 + j0 + jl) * 64 + lane) * 8,
                &bs[s * 512]);
  }

  const int t0 = tidx * 2;
  const float* xr0 = x + ((size_t)t0 * 128 + w * 16 + l15) * 256;
  const float* xr1 = xr0 + 128 * 256;

  float4 xc[16], xn[16];
#pragma unroll
  for (int c = 0; c < 8; ++c) {
    xc[2 * c]     = *reinterpret_cast<const float4*>(xr0 + c * 32 + g * 8);
    xc[2 * c + 1] = *reinterpret_cast<const float4*>(xr0 + c * 32 + g * 8 + 4);
  }
  asm volatile("s_waitcnt vmcnt(0)" ::: "memory");   // weights + tile0 x done
  __syncthreads();

  // issue tile-1 x loads; they fly during tile-0 compute
#pragma unroll
  for (int c = 0; c < 8; ++c) {
    xn[2 * c]     = *reinterpret_cast<const float4*>(xr1 + c * 32 + g * 8);
    xn[2 * c + 1] = *reinterpret_cast<const float4*>(xr1 + c * 32 + g * 8 + 4);
  }

#define KV_TILE(XR, TILE)                                                     \
  {                                                                           \
    f32x4 acc[8];                                                             \
    _Pragma("unroll") for (int j = 0; j < 8; ++j) acc[j] = zero4();           \
    _Pragma("unroll") for (int c = 0; c < 8; ++c) {                           \
      bf16x8 a;                                                               \
      a[0] = f2bf(XR[2 * c].x);     a[1] = f2bf(XR[2 * c].y);                 \
      a[2] = f2bf(XR[2 * c].z);     a[3] = f2bf(XR[2 * c].w);                 \
      a[4] = f2bf(XR[2 * c + 1].x); a[5] = f2bf(XR[2 * c + 1].y);             \
      a[6] = f2bf(XR[2 * c + 1].z); a[7] = f2bf(XR[2 * c + 1].w);             \
      _Pragma("unroll") for (int j = 0; j < 8; ++j) {                         \
        bf16x8 bj =                                                           \
            *reinterpret_cast<const bf16x8*>(&bs[((c * 8 + j) * 64 + lane) * 8]); \
        acc[j] = mfma_bf16(a, bj, acc[j]);                                    \
      }                                                                       \
    }                                                                         \
    const int row0 = (TILE) * 128 + w * 16 + g * 4;                           \
    const int bb_ = row0 / 196, n0 = row0 % 196;                              \
    _Pragma("unroll") for (int j = 0; j < 8; ++j) {                           \
      const int jg = j0 + j;                                                  \
      const int h = jg / 3, part = jg % 3;                                    \
      const float bv = bias[jg * 16 + l15];                                   \
      if (part == 0) {                                                        \
        short* kp = k_out + ((size_t)(bb_ * 8 + h) * 196 + n0) * 16 + l15;    \
        _Pragma("unroll") for (int r = 0; r < 4; ++r)                         \
            kp[r * 16] = f2bf(acc[j][r] + bv);                                \
      } else {                                                                \
        const int d = (part - 1) * 16 + l15;                                  \
        short4v sv;                                                           \
        _Pragma("unroll") for (int r = 0; r < 4; ++r)                         \
            sv[r] = f2bf(acc[j][r] + bv);                                     \
        *reinterpret_cast<short4v*>(                                          \
            vT_out + ((size_t)(bb_ * 8 + h) * 32 + d) * 196 + n0) = sv;       \
      }                                                                       \
    }                                                                         \
  }

  KV_TILE(xc, t0)
  KV_TILE(xn, t0 + 1)
#undef KV_TILE
}

// ---------------------------------------------------------------------------
// Kernel 2: q = xs @ pk_q + bias -> bf16 (B*49, 128). grid = 392.
// ---------------------------------------------------------------------------
__global__ __launch_bounds__(256) void q_gemm2(
    const float* __restrict__ x, const short* __restrict__ pk,
    const float* __restrict__ bias, short* __restrict__ out) {
  __shared__ short bs[8 * 512];
  __shared__ float sb[128];
  const int tid = threadIdx.x, w_id = tid >> 6, lane = tid & 63;
  const int l15 = lane & 15, gq = lane >> 4;
  const int mt = blockIdx.x;
  if (tid < 128) sb[tid] = bias[tid];
  const int arow = mt * 64 + w_id * 16 + l15;
  const int b = arow / 49, qi = arow % 49;
  const int n = 28 * (qi / 7) + 2 * (qi % 7);
  const float* xrow = x + ((size_t)b * 196 + n) * 256;

  f32x4 acc[8];
#pragma unroll
  for (int j = 0; j < 8; ++j) acc[j] = zero4();

  for (int c = 0; c < 8; ++c) {
    for (int seg = w_id; seg < 8; seg += 4)
      gload_lds16(pk + ((size_t)(c * 8 + seg) * 64 + lane) * 8, &bs[seg * 512]);
    const float4 u0 = *reinterpret_cast<const float4*>(xrow + c * 32 + gq * 8);
    const float4 u1 = *reinterpret_cast<const float4*>(xrow + c * 32 + gq * 8 + 4);
    bf16x8 a;
    a[0] = f2bf(u0.x); a[1] = f2bf(u0.y); a[2] = f2bf(u0.z); a[3] = f2bf(u0.w);
    a[4] = f2bf(u1.x); a[5] = f2bf(u1.y); a[6] = f2bf(u1.z); a[7] = f2bf(u1.w);
    __syncthreads();
#pragma unroll
    for (int j = 0; j < 8; ++j) {
      bf16x8 bj = *reinterpret_cast<const bf16x8*>(&bs[(j * 64 + lane) * 8]);
      acc[j] = mfma_bf16(a, bj, acc[j]);
    }
    __syncthreads();
  }
  const int orow = mt * 64 + w_id * 16 + gq * 4;
#pragma unroll
  for (int j = 0; j < 8; ++j) {
    int ch = j * 16 + l15;
    float bb = sb[ch];
#pragma unroll
    for (int r = 0; r < 4; ++r)
      out[(size_t)(orow + r) * 128 + ch] = f2bf(acc[j][r] + bb);
  }
}

// ---------------------------------------------------------------------------
// Kernel 2b: ab_full[h][q][n] = ab_table[h][bias_idxs[q][n]]
// ---------------------------------------------------------------------------
__global__ void ab_gather_k(const float* __restrict__ tab,
                            const int* __restrict__ idxs,
                            float* __restrict__ out, int n_off) {
  const int hq = blockIdx.x;
  const int h = hq / 49, q = hq % 49;
  const int t = threadIdx.x;
  if (t < 196)
    out[(size_t)hq * 196 + t] = tab[h * n_off + idxs[q * 196 + t]];
}

// ---------------------------------------------------------------------------
// Kernel 3: swapped-operand attention; V^T slab gload_lds-staged, K from
// compact k_ws, P in registers. grid = 4096 (b,h), 256 thr.
// ---------------------------------------------------------------------------
__global__ __launch_bounds__(256) void attn3_k(
    const short* __restrict__ k_ws, const short* __restrict__ vT_ws,
    const short* __restrict__ qw, const float* __restrict__ ab,
    short* __restrict__ out) {
  __shared__ short vt[6304];   // [32][196] packed (12544 B) + 64 B guard
  const int b = blockIdx.x >> 3, h = blockIdx.x & 7;
  const int tid = threadIdx.x, w_id = tid >> 6, lane = tid & 63;
  const int l15 = lane & 15, g = lane >> 4;

  if (tid < 16) *reinterpret_cast<unsigned int*>(&vt[6272 + tid * 2]) = 0u;

  const short* vsrc = vT_ws + (size_t)(b * 8 + h) * 6272;
  for (int s = w_id; s < 13; s += 4) {
    if (s * 64 + lane < 784)
      gload_lds16(vsrc + (size_t)(s * 64 + lane) * 8, &vt[s * 512]);
  }

  const short* kslab = k_ws + (size_t)(b * 8 + h) * 3136;   // [196][16]

  const int q = w_id * 16 + l15;
  const bool qok = q < 49;
  bf16x8 bq = zero8();
  if (g < 2 && qok)
    bq = *reinterpret_cast<const bf16x8*>(
        qw + ((size_t)b * 49 + q) * 128 + h * 16 + g * 8);

  f32x4 s[13];
#pragma unroll
  for (int t = 0; t < 13; ++t) {
    int n_a = (t >> 1) * 32 + (l15 >> 2) * 8 + (t & 1) * 4 + (l15 & 3);
    bf16x8 ak = zero8();
    if (g < 2 && n_a < 196)
      ak = *reinterpret_cast<const bf16x8*>(kslab + (size_t)n_a * 16 + g * 8);
    s[t] = mfma_bf16(ak, bq, zero4());
  }

  const float* abrow = ab + ((size_t)h * 49 + (qok ? q : 0)) * 196;
#pragma unroll
  for (int t = 0; t < 13; ++t) {
    int nb = (t >> 1) * 32 + g * 8 + (t & 1) * 4;
    if (nb < 196) {
      const float4 bi = *reinterpret_cast<const float4*>(abrow + nb);
      s[t][0] = s[t][0] * 0.25f + bi.x;
      s[t][1] = s[t][1] * 0.25f + bi.y;
      s[t][2] = s[t][2] * 0.25f + bi.z;
      s[t][3] = s[t][3] * 0.25f + bi.w;
    } else {
      s[t][0] = -1e30f; s[t][1] = -1e30f; s[t][2] = -1e30f; s[t][3] = -1e30f;
    }
  }

  float mx = s[0][0];
#pragma unroll
  for (int t = 0; t < 13; ++t)
    mx = fmaxf(mx, fmaxf(fmaxf(s[t][0], s[t][1]), fmaxf(s[t][2], s[t][3])));
  mx = fmaxf(mx, __shfl_xor(mx, 16, 64));
  mx = fmaxf(mx, __shfl_xor(mx, 32, 64));
  float sum = 0.f;
#pragma unroll
  for (int t = 0; t < 13; ++t) {
#pragma unroll
    for (int r = 0; r < 4; ++r) {
      float e = __expf(s[t][r] - mx);
      s[t][r] = e;
      sum += e;
    }
  }
  sum += __shfl_xor(sum, 16, 64);
  sum += __shfl_xor(sum, 32, 64);
  const float inv = 1.f / sum;

  unsigned int pkr[14][2];
#pragma unroll
  for (int t = 0; t < 13; ++t) {
    pkr[t][0] = pack2bf(s[t][0] * inv, s[t][1] * inv);
    pkr[t][1] = pack2bf(s[t][2] * inv, s[t][3] * inv);
  }
  pkr[13][0] = 0u; pkr[13][1] = 0u;

  __syncthreads();   // V^T staged

  f32x4 o0 = zero4(), o1 = zero4();
#pragma unroll
  for (int c = 0; c < 7; ++c) {
    u32x4 bp_u;
    bp_u[0] = pkr[2 * c][0];     bp_u[1] = pkr[2 * c][1];
    bp_u[2] = pkr[2 * c + 1][0]; bp_u[3] = pkr[2 * c + 1][1];
    bf16x8 bp = __builtin_bit_cast(bf16x8, bp_u);
    bf16x8 a0 = lds8(&vt[l15 * 196 + c * 32 + g * 8]);
    bf16x8 a1 = lds8(&vt[(16 + l15) * 196 + c * 32 + g * 8]);
    o0 = mfma_bf16(a0, bp, o0);
    o1 = mfma_bf16(a1, bp, o1);
  }

  if (qok) {
    short* op = out + (((size_t)b * 49 + q) * 256 + h * 32 + g * 4);
    short4v v0, v1;
#pragma unroll
    for (int r = 0; r < 4; ++r) {
      float x0 = o0[r];
      v0[r] = f2bf(x0 * fminf(fmaxf(x0 + 3.f, 0.f), 6.f) * (1.f / 6.f));
      float x1 = o1[r];
      v1[r] = f2bf(x1 * fminf(fmaxf(x1 + 3.f, 0.f), 6.f) * (1.f / 6.f));
    }
    *reinterpret_cast<short4v*>(op) = v0;
    *reinterpret_cast<short4v*>(op + 16) = v1;
  }
}

// ---------------------------------------------------------------------------
// Kernel 4: out = at @ pk_p + bias -> f32 (B*49, 512). grid = 392*2.
// ---------------------------------------------------------------------------
__global__ __launch_bounds__(256) void p_gemm2(
    const short* __restrict__ a_in, const short* __restrict__ pk,
    const float* __restrict__ bias, float* __restrict__ out) {
  __shared__ short bs[16 * 512];
  __shared__ float sb[256];
  const int tid = threadIdx.x, w_id = tid >> 6, lane = tid & 63;
  const int l15 = lane & 15, gq = lane >> 4;
  const int half = blockIdx.x & 1;
  const int mt = blockIdx.x >> 1;
  for (int i = tid; i < 256; i += 256) sb[i] = bias[half * 256 + i];
  const int arow = mt * 64 + w_id * 16 + l15;
  const short* arp = a_in + (size_t)arow * 256;

  f32x4 acc[16];
#pragma unroll
  for (int j = 0; j < 16; ++j) acc[j] = zero4();

  for (int c = 0; c < 8; ++c) {
    for (int seg = w_id; seg < 16; seg += 4)
      gload_lds16(pk + ((size_t)(c * 32 + half * 16 + seg) * 64 + lane) * 8,
                  &bs[seg * 512]);
    bf16x8 a = *reinterpret_cast<const bf16x8*>(arp + c * 32 + gq * 8);
    __syncthreads();
#pragma unroll
    for (int j = 0; j < 16; ++j) {
      bf16x8 bj = *reinterpret_cast<const bf16x8*>(&bs[(j * 64 + lane) * 8]);
      acc[j] = mfma_bf16(a, bj, acc[j]);
    }
    __syncthreads();
  }
  const int orow = mt * 64 + w_id * 16 + gq * 4;
#pragma unroll
  for (int j = 0; j < 16; ++j) {
    int chl = j * 16 + l15;
    float bb = sb[chl];
    int och = half * 256 + chl;
#pragma unroll
    for (int r = 0; r < 4; ++r)
      out[(size_t)(orow + r) * 512 + och] = acc[j][r] + bb;
  }
}

// ---------------------------------------------------------------------------
extern "C" void kernel_launch(void* const* d_in, const int* in_sizes, int n_in,
                              void* d_out, int out_size, void* d_ws, size_t ws_size,
                              hipStream_t stream) {
  const float* x    = (const float*)d_in[0];
  const float* w_kv = (const float*)d_in[1];
  const float* kv_g = (const float*)d_in[2];
  const float* kv_b = (const float*)d_in[3];
  const float* kv_m = (const float*)d_in[4];
  const float* kv_v = (const float*)d_in[5];
  const float* w_q  = (const float*)d_in[6];
  const float* q_g  = (const float*)d_in[7];
  const float* q_b  = (const float*)d_in[8];
  const float* q_m  = (const float*)d_in[9];
  const float* q_v  = (const float*)d_in[10];
  const float* w_p  = (const float*)d_in[11];
  const float* p_g  = (const float*)d_in[12];
  const float* p_b  = (const float*)d_in[13];
  const float* p_m  = (const float*)d_in[14];
  const float* p_v  = (const float*)d_in[15];
  const float* ab_t = (const float*)d_in[16];
  const int*   idxs = (const int*)d_in[17];
  const int n_off = in_sizes[16] / 8;

  char* ws = (char*)d_ws;
  short* pk_kv  = (short*)(ws);                    //    196,608
  short* pk_q   = (short*)(ws + 196608);           //     65,536
  short* pk_p   = (short*)(ws + 262144);           //    262,144
  float* bs_kv  = (float*)(ws + 524288);           //      1,536
  float* bs_q   = (float*)(ws + 525824);           //        512
  float* bs_p   = (float*)(ws + 526336);           //      2,048
  float* ab_ws  = (float*)(ws + 528384);           //    307,328 -> 835,712
  short* k_ws   = (short*)(ws + 835712);           // 25,690,112 -> 26,525,824
  short* vT_ws  = (short*)(ws + 26525824);         // 51,380,224 -> 77,906,048
  short* q_ws   = (short*)(ws + 77906048);         //  6,422,528 -> 84,328,576
  short* at_ws  = (short*)(ws + 84328576);         // 12,845,056 -> 97,173,632

  pack_w_k<<<dim3(48), dim3(256), 0, stream>>>(w_kv, kv_g, kv_b, kv_m, kv_v, pk_kv, bs_kv, 384);
  pack_w_k<<<dim3(16), dim3(256), 0, stream>>>(w_q, q_g, q_b, q_m, q_v, pk_q, bs_q, 128);
  pack_w_k<<<dim3(64), dim3(256), 0, stream>>>(w_p, p_g, p_b, p_m, p_v, pk_p, bs_p, 512);
  ab_gather_k<<<dim3(392), dim3(256), 0, stream>>>(ab_t, idxs, ab_ws, n_off);

  kv_gemm4<<<dim3(1176), dim3(512), 0, stream>>>(x, pk_kv, bs_kv, k_ws, vT_ws);
  q_gemm2<<<dim3(392), dim3(256), 0, stream>>>(x, pk_q, bs_q, q_ws);
  attn3_k<<<dim3(4096), dim3(256), 0, stream>>>(k_ws, vT_ws, q_ws, ab_ws, at_ws);
  p_gemm2<<<dim3(784), dim3(256), 0, stream>>>(at_ws, pk_p, bs_p, (float*)d_out);
}

// Round 6
// 142.016 us; speedup vs baseline: 1.3122x; 1.3122x over previous
//
#include <hip/hip_runtime.h>

typedef __attribute__((ext_vector_type(8))) short bf16x8;
typedef __attribute__((ext_vector_type(4))) float f32x4;
typedef __attribute__((ext_vector_type(4))) short short4v;
typedef __attribute__((ext_vector_type(4))) unsigned int u32x4;

#define DEVFN static __device__ __forceinline__

DEVFN short f2bf(float f) {
  unsigned int u = __builtin_bit_cast(unsigned int, f);
  unsigned int r = (u + 0x7FFFu + ((u >> 16) & 1u)) >> 16;   // RNE
  return (short)r;
}

DEVFN unsigned int pack2bf(float a, float b) {
  unsigned int lo = (unsigned int)(unsigned short)f2bf(a);
  unsigned int hi = (unsigned int)(unsigned short)f2bf(b);
  return lo | (hi << 16);
}

DEVFN f32x4 mfma_bf16(bf16x8 a, bf16x8 b, f32x4 c) {
  return __builtin_amdgcn_mfma_f32_16x16x32_bf16(a, b, c, 0, 0, 0);
}

DEVFN f32x4 zero4() { f32x4 z = {0.f, 0.f, 0.f, 0.f}; return z; }
DEVFN bf16x8 zero8() { bf16x8 z = {0,0,0,0,0,0,0,0}; return z; }

// 8B-aligned LDS read of 8 bf16 (two b64s)
DEVFN bf16x8 lds8(const short* p) {
  short4v lo = *reinterpret_cast<const short4v*>(p);
  short4v hi = *reinterpret_cast<const short4v*>(p + 4);
  bf16x8 r;
  r[0] = lo[0]; r[1] = lo[1]; r[2] = lo[2]; r[3] = lo[3];
  r[4] = hi[0]; r[5] = hi[1]; r[6] = hi[2]; r[7] = hi[3];
  return r;
}

// ---------------------------------------------------------------------------
// Weight pack: fold BN scale, cvt bf16, fragment-major layout
// pk[((c*(O/16)+j)*64+lane)*8+e] = w[j*16+(lane&15)][c*32+(lane>>4)*8+e]*s
// ---------------------------------------------------------------------------
__global__ void pack_w_k(const float* __restrict__ w, const float* __restrict__ g,
                         const float* __restrict__ b, const float* __restrict__ m,
                         const float* __restrict__ v, short* __restrict__ pk,
                         float* __restrict__ bias, int O) {
  const int t = blockIdx.x * 256 + threadIdx.x;
  const int nt = O >> 4;
  const int total = nt * 8 * 64;
  if (t < total) {
    int lane = t & 63;
    int j = (t >> 6) % nt;
    int c = (t >> 6) / nt;
    int row = j * 16 + (lane & 15);
    int col = c * 32 + (lane >> 4) * 8;
    float s = g[row] * rsqrtf(v[row] + 1e-5f);
    const float* wp = w + (size_t)row * 256 + col;
    short* o = pk + (size_t)t * 8;
#pragma unroll
    for (int e = 0; e < 8; ++e) o[e] = f2bf(wp[e] * s);
  }
  if (t < O) {
    float s = g[t] * rsqrtf(v[t] + 1e-5f);
    bias[t] = b[t] - m[t] * s;
  }
}

// ---------------------------------------------------------------------------
// ab_full[h][q][n] = ab_table[h][bias_idxs[q][n]]
// ---------------------------------------------------------------------------
__global__ void ab_gather_k(const float* __restrict__ tab,
                            const int* __restrict__ idxs,
                            float* __restrict__ out, int n_off) {
  const int hq = blockIdx.x;
  const int h = hq / 49, q = hq % 49;
  const int t = threadIdx.x;
  if (t < 196)
    out[(size_t)hq * 196 + t] = tab[h * n_off + idxs[q * 196 + t]];
}

// ---------------------------------------------------------------------------
// Fully fused per-batch kernel. One block per b (512 blocks, 256 thr, 4 waves).
// LDS (shorts): xs [196][256] swizzled | ks [196][20] | vs [32][196]+guard |
//               qs [49][128] swizzled  | as_ [52][256] swizzled
// ---------------------------------------------------------------------------
__global__ __launch_bounds__(256, 1) void fused_k(
    const float* __restrict__ x,
    const short* __restrict__ pkv, const float* __restrict__ bkv,
    const short* __restrict__ pq,  const float* __restrict__ bq_,
    const short* __restrict__ pp,  const float* __restrict__ bp_,
    const float* __restrict__ ab,  float* __restrict__ out) {
  __shared__ short lds[79984];   // 159,968 B
  short* xs  = lds;              // 50176 sh
  short* ks  = lds + 50176;      //  3920 sh ([196] rows of 20 shorts)
  short* vs  = lds + 54096;      //  6304 sh ([32][196] + 32 guard)
  short* qs  = lds + 60400;      //  6272 sh
  short* as_ = lds + 66672;      // 13312 sh ([52][256])

  const int b = blockIdx.x;
  const int tid = threadIdx.x, w = tid >> 6, lane = tid & 63;
  const int l15 = lane & 15, g = lane >> 4;

  // ---- P0: stage x[b] -> bf16 LDS, swizzled; zero vt guard ----
  if (tid < 32) vs[6272 + tid] = 0;
  const float* xb = x + (size_t)b * 196 * 256;
  for (int i = tid; i < 6272; i += 256) {
    int row = i >> 5, gc = i & 31;
    const float* src = xb + row * 256 + gc * 8;
    float4 u0 = *reinterpret_cast<const float4*>(src);
    float4 u1 = *reinterpret_cast<const float4*>(src + 4);
    bf16x8 vv;
    vv[0] = f2bf(u0.x); vv[1] = f2bf(u0.y); vv[2] = f2bf(u0.z); vv[3] = f2bf(u0.w);
    vv[4] = f2bf(u1.x); vv[5] = f2bf(u1.y); vv[6] = f2bf(u1.z); vv[7] = f2bf(u1.w);
    int ob = (gc * 16) ^ ((row & 7) << 4);
    *reinterpret_cast<bf16x8*>(reinterpret_cast<char*>(xs) + row * 512 + ob) = vv;
  }
  __syncthreads();

#define XFRAG(row, c)                                                         \
  (*reinterpret_cast<const bf16x8*>(                                          \
      reinterpret_cast<const char*>(xs) + (row) * 512 +                       \
      (((c) * 64 + g * 16) ^ (((row) & 7) << 4))))

  // ---- P1: q-gemm. wave w -> j {2w, 2w+1}, all 4 M-tiles ----
  {
    f32x4 qa[4][2];
#pragma unroll
    for (int mt = 0; mt < 4; ++mt) { qa[mt][0] = zero4(); qa[mt][1] = zero4(); }
#pragma unroll
    for (int c = 0; c < 8; ++c) {
      bf16x8 w0 = *reinterpret_cast<const bf16x8*>(pq + ((size_t)(c * 8 + 2 * w) * 64 + lane) * 8);
      bf16x8 w1 = *reinterpret_cast<const bf16x8*>(pq + ((size_t)(c * 8 + 2 * w + 1) * 64 + lane) * 8);
#pragma unroll
      for (int mt = 0; mt < 4; ++mt) {
        int qi = mt * 16 + l15; if (qi > 48) qi = 48;
        int xr = 28 * (qi / 7) + 2 * (qi % 7);
        bf16x8 a = XFRAG(xr, c);
        qa[mt][0] = mfma_bf16(a, w0, qa[mt][0]);
        qa[mt][1] = mfma_bf16(a, w1, qa[mt][1]);
      }
    }
#pragma unroll
    for (int mt = 0; mt < 4; ++mt) {
#pragma unroll
      for (int jj = 0; jj < 2; ++jj) {
        int ch = (2 * w + jj) * 16 + l15;
        float bv = bq_[ch];
#pragma unroll
        for (int r = 0; r < 4; ++r) {
          int q = mt * 16 + g * 4 + r;
          if (q < 49)
            *reinterpret_cast<short*>(reinterpret_cast<char*>(qs) + q * 256 +
                                      ((ch * 2) ^ ((q & 7) << 4))) =
                f2bf(qa[mt][jj][r] + bv);
        }
      }
    }
  }
  __syncthreads();

  // ---- P2: per-head kv-gemm + attention ----
  for (int h = 0; h < 8; ++h) {
    {
      // preload this head's 24 weight fragments (K:j0, V:j1,j2)
      bf16x8 wf0[8], wf1[8], wf2[8];
#pragma unroll
      for (int c = 0; c < 8; ++c) {
        wf0[c] = *reinterpret_cast<const bf16x8*>(pkv + ((size_t)(c * 24 + 3 * h) * 64 + lane) * 8);
        wf1[c] = *reinterpret_cast<const bf16x8*>(pkv + ((size_t)(c * 24 + 3 * h + 1) * 64 + lane) * 8);
        wf2[c] = *reinterpret_cast<const bf16x8*>(pkv + ((size_t)(c * 24 + 3 * h + 2) * 64 + lane) * 8);
      }
      float bvK = bkv[3 * h * 16 + l15];
      float4 bv0 = *reinterpret_cast<const float4*>(bkv + (3 * h + 1) * 16 + g * 4);
      float4 bv1 = *reinterpret_cast<const float4*>(bkv + (3 * h + 2) * 16 + g * 4);
#pragma unroll
      for (int ti = 0; ti < 4; ++ti) {
        const int mt = (ti < 3) ? (w + ti * 4) : 12;
        const bool active = (ti < 3) || (w == 0);
        if (active) {
          f32x4 aK = zero4(), a0 = zero4(), a1 = zero4();
          int xr = mt * 16 + l15; if (xr > 195) xr = 195;
#pragma unroll
          for (int c = 0; c < 8; ++c) {
            bf16x8 a = XFRAG(xr, c);
            aK = mfma_bf16(a, wf0[c], aK);    // K[n][kd]
            a0 = mfma_bf16(wf1[c], a, a0);    // V^T[d0..15][n]
            a1 = mfma_bf16(wf2[c], a, a1);    // V^T[d16..31][n]
          }
#pragma unroll
          for (int r = 0; r < 4; ++r) {
            int n = mt * 16 + g * 4 + r;
            if (n < 196) ks[n * 20 + l15] = f2bf(aK[r] + bvK);
          }
          int nv = mt * 16 + l15;
          if (nv < 196) {
#pragma unroll
            for (int r = 0; r < 4; ++r)
              vs[(g * 4 + r) * 196 + nv] = f2bf(a0[r] + bv0[r]);
#pragma unroll
            for (int r = 0; r < 4; ++r)
              vs[(16 + g * 4 + r) * 196 + nv] = f2bf(a1[r] + bv1[r]);
          }
        }
      }
    }
    __syncthreads();   // k/v slab ready

    // ---- attention, q-tile = w ----
    {
      int qm = w * 16 + l15; if (qm > 48) qm = 48;
      bf16x8 bq = zero8();
      if (g < 2)
        bq = *reinterpret_cast<const bf16x8*>(
            reinterpret_cast<const char*>(qs) + qm * 256 +
            ((h * 32 + g * 16) ^ ((qm & 7) << 4)));

      f32x4 s[13];
#pragma unroll
      for (int t = 0; t < 13; ++t) {
        int n_a = (t >> 1) * 32 + (l15 >> 2) * 8 + (t & 1) * 4 + (l15 & 3);
        bf16x8 ak = zero8();
        if (g < 2 && n_a < 196) ak = lds8(ks + n_a * 20 + g * 8);
        s[t] = mfma_bf16(ak, bq, zero4());
      }

      const float* abrow = ab + ((size_t)h * 49 + qm) * 196;
#pragma unroll
      for (int t = 0; t < 13; ++t) {
        int nb = (t >> 1) * 32 + g * 8 + (t & 1) * 4;
        if (nb < 196) {
          const float4 bi = *reinterpret_cast<const float4*>(abrow + nb);
          s[t][0] = s[t][0] * 0.25f + bi.x;
          s[t][1] = s[t][1] * 0.25f + bi.y;
          s[t][2] = s[t][2] * 0.25f + bi.z;
          s[t][3] = s[t][3] * 0.25f + bi.w;
        } else {
          s[t][0] = -1e30f; s[t][1] = -1e30f; s[t][2] = -1e30f; s[t][3] = -1e30f;
        }
      }

      float mx = s[0][0];
#pragma unroll
      for (int t = 0; t < 13; ++t)
        mx = fmaxf(mx, fmaxf(fmaxf(s[t][0], s[t][1]), fmaxf(s[t][2], s[t][3])));
      mx = fmaxf(mx, __shfl_xor(mx, 16, 64));
      mx = fmaxf(mx, __shfl_xor(mx, 32, 64));
      float sum = 0.f;
#pragma unroll
      for (int t = 0; t < 13; ++t) {
#pragma unroll
        for (int r = 0; r < 4; ++r) {
          float e = __expf(s[t][r] - mx);
          s[t][r] = e;
          sum += e;
        }
      }
      sum += __shfl_xor(sum, 16, 64);
      sum += __shfl_xor(sum, 32, 64);
      const float inv = 1.f / sum;

      unsigned int pkr[14][2];
#pragma unroll
      for (int t = 0; t < 13; ++t) {
        pkr[t][0] = pack2bf(s[t][0] * inv, s[t][1] * inv);
        pkr[t][1] = pack2bf(s[t][2] * inv, s[t][3] * inv);
      }
      pkr[13][0] = 0u; pkr[13][1] = 0u;

      f32x4 o0 = zero4(), o1 = zero4();
#pragma unroll
      for (int c = 0; c < 7; ++c) {
        u32x4 bp_u;
        bp_u[0] = pkr[2 * c][0];     bp_u[1] = pkr[2 * c][1];
        bp_u[2] = pkr[2 * c + 1][0]; bp_u[3] = pkr[2 * c + 1][1];
        bf16x8 bp = __builtin_bit_cast(bf16x8, bp_u);
        bf16x8 v0 = lds8(vs + l15 * 196 + c * 32 + g * 8);
        bf16x8 v1 = lds8(vs + (16 + l15) * 196 + c * 32 + g * 8);
        o0 = mfma_bf16(bp, v0, o0);   // P as A-operand -> O[q][d]
        o1 = mfma_bf16(bp, v1, o1);
      }

#pragma unroll
      for (int r = 0; r < 4; ++r) {
        int q2 = w * 16 + g * 4 + r;
        if (q2 < 52) {
          float x0 = o0[r];
          float h0 = x0 * fminf(fmaxf(x0 + 3.f, 0.f), 6.f) * (1.f / 6.f);
          float x1 = o1[r];
          float h1 = x1 * fminf(fmaxf(x1 + 3.f, 0.f), 6.f) * (1.f / 6.f);
          char* base = reinterpret_cast<char*>(as_) + q2 * 512;
          int sw = (q2 & 7) << 4;
          *reinterpret_cast<short*>(base + ((h * 64 + l15 * 2) ^ sw)) = f2bf(h0);
          *reinterpret_cast<short*>(base + ((h * 64 + 32 + l15 * 2) ^ sw)) = f2bf(h1);
        }
      }
    }
    __syncthreads();   // slab consumed; at-slice written
  }

  // ---- P3: p-gemm. wave w -> j-slice w*8..w*8+7, all 4 M-tiles ----
  {
    f32x4 pa[4][8];
#pragma unroll
    for (int mt = 0; mt < 4; ++mt)
#pragma unroll
      for (int j = 0; j < 8; ++j) pa[mt][j] = zero4();

#pragma unroll
    for (int c = 0; c < 8; ++c) {
      bf16x8 wp[8];
#pragma unroll
      for (int j = 0; j < 8; ++j)
        wp[j] = *reinterpret_cast<const bf16x8*>(pp + ((size_t)(c * 32 + w * 8 + j) * 64 + lane) * 8);
#pragma unroll
      for (int mt = 0; mt < 4; ++mt) {
        int rb = (mt < 3) ? mt * 16 : 36;
        int row = rb + l15;
        bf16x8 a = *reinterpret_cast<const bf16x8*>(
            reinterpret_cast<const char*>(as_) + row * 512 +
            ((c * 64 + g * 16) ^ ((row & 7) << 4)));
#pragma unroll
        for (int j = 0; j < 8; ++j) pa[mt][j] = mfma_bf16(a, wp[j], pa[mt][j]);
      }
    }

#pragma unroll
    for (int mt = 0; mt < 4; ++mt) {
      int rb = (mt < 3) ? mt * 16 : 36;
#pragma unroll
      for (int j = 0; j < 8; ++j) {
        float bv = bp_[w * 128 + j * 16 + l15];
#pragma unroll
        for (int r = 0; r < 4; ++r) {
          int q2 = rb + g * 4 + r;
          if (q2 < 49 && (mt < 3 || q2 >= 48))
            out[((size_t)b * 49 + q2) * 512 + w * 128 + j * 16 + l15] =
                pa[mt][j][r] + bv;
        }
      }
    }
  }
#undef XFRAG
}

// ---------------------------------------------------------------------------
extern "C" void kernel_launch(void* const* d_in, const int* in_sizes, int n_in,
                              void* d_out, int out_size, void* d_ws, size_t ws_size,
                              hipStream_t stream) {
  const float* x    = (const float*)d_in[0];
  const float* w_kv = (const float*)d_in[1];
  const float* kv_g = (const float*)d_in[2];
  const float* kv_b = (const float*)d_in[3];
  const float* kv_m = (const float*)d_in[4];
  const float* kv_v = (const float*)d_in[5];
  const float* w_q  = (const float*)d_in[6];
  const float* q_g  = (const float*)d_in[7];
  const float* q_b  = (const float*)d_in[8];
  const float* q_m  = (const float*)d_in[9];
  const float* q_v  = (const float*)d_in[10];
  const float* w_p  = (const float*)d_in[11];
  const float* p_g  = (const float*)d_in[12];
  const float* p_b  = (const float*)d_in[13];
  const float* p_m  = (const float*)d_in[14];
  const float* p_v  = (const float*)d_in[15];
  const float* ab_t = (const float*)d_in[16];
  const int*   idxs = (const int*)d_in[17];
  const int n_off = in_sizes[16] / 8;

  char* ws = (char*)d_ws;
  short* pk_kv = (short*)(ws);                 // 196,608
  short* pk_q  = (short*)(ws + 196608);        //  65,536
  short* pk_p  = (short*)(ws + 262144);        // 262,144
  float* bs_kv = (float*)(ws + 524288);        //   1,536
  float* bs_q  = (float*)(ws + 525824);        //     512
  float* bs_p  = (float*)(ws + 526336);        //   2,048
  float* ab_ws = (float*)(ws + 528384);        // 307,328 -> 835,712

  pack_w_k<<<dim3(48), dim3(256), 0, stream>>>(w_kv, kv_g, kv_b, kv_m, kv_v, pk_kv, bs_kv, 384);
  pack_w_k<<<dim3(16), dim3(256), 0, stream>>>(w_q, q_g, q_b, q_m, q_v, pk_q, bs_q, 128);
  pack_w_k<<<dim3(64), dim3(256), 0, stream>>>(w_p, p_g, p_b, p_m, p_v, pk_p, bs_p, 512);
  ab_gather_k<<<dim3(392), dim3(256), 0, stream>>>(ab_t, idxs, ab_ws, n_off);

  fused_k<<<dim3(512), dim3(256), 0, stream>>>(
      x, pk_kv, bs_kv, pk_q, bs_q, pk_p, bs_p, ab_ws, (float*)d_out);
}